// Round 4
// baseline (608.723 us; speedup 1.0000x reference)
//
#include <hip/hip_runtime.h>

#define BB 4
#define SS 2048
#define HH 4
#define DD 192
#define QT 16
#define NEG_BIG (-1e9f)

typedef __attribute__((ext_vector_type(8))) short short8;
typedef __attribute__((ext_vector_type(4))) float f32x4;

__device__ inline ushort f2bf(float x) {
    union { float f; unsigned u; } v; v.f = x;
    unsigned r = (v.u + 0x7FFFu + ((v.u >> 16) & 1u)) >> 16;
    return (ushort)r;
}
// wave-local LDS fence: drain DS queue + compiler barrier (no block barrier)
__device__ inline void wave_lds_fence() {
    __builtin_amdgcn_wave_barrier();
    __builtin_amdgcn_s_waitcnt(0xC07F);   // vmcnt(63) expcnt(7) lgkmcnt(0)
    __builtin_amdgcn_wave_barrier();
}

// ---------------------------------------------------------------------------
// Transpose the four weight matrices: WT[c][j] = W[j][c].  grid (6,6,4).
// ---------------------------------------------------------------------------
__global__ __launch_bounds__(256) void wt_kernel(
    const float* __restrict__ Wq, const float* __restrict__ Wk,
    const float* __restrict__ Wv, const float* __restrict__ Wo,
    float* __restrict__ WTall)
{
    __shared__ float tile[32][33];
    const float* W = (blockIdx.z == 0) ? Wq : (blockIdx.z == 1) ? Wk
                   : (blockIdx.z == 2) ? Wv : Wo;
    float* WT = WTall + (size_t)blockIdx.z * DD * DD;
    const int c0 = blockIdx.x * 32, j0 = blockIdx.y * 32;
    const int tx = threadIdx.x & 31, ty = threadIdx.x >> 5;
#pragma unroll
    for (int k = 0; k < 4; ++k)
        tile[ty + 8 * k][tx] = W[(size_t)(j0 + ty + 8 * k) * DD + c0 + tx];
    __syncthreads();
#pragma unroll
    for (int k = 0; k < 4; ++k)
        WT[(size_t)(c0 + ty + 8 * k) * DD + j0 + tx] = tile[tx][ty + 8 * k];
}

// ---------------------------------------------------------------------------
// Fused QKV projection via WT. 384 thr (6 waves), 32 rows/block, grid(256,3).
// Thread: cols jt..jt+3, rows rowg*4..rowg*4+3.
// ---------------------------------------------------------------------------
__global__ __launch_bounds__(384) void qkv_proj_kernel(
    const float* __restrict__ Xq, const float* __restrict__ Xk,
    const float* __restrict__ Xv, const float* __restrict__ WTall,
    ushort* __restrict__ qpad, ushort* __restrict__ kpad,
    ushort* __restrict__ vT)
{
    const int mode = blockIdx.y;
    const float* __restrict__ X = (mode == 0) ? Xq : (mode == 1) ? Xk : Xv;
    const float* __restrict__ WT = WTall + (size_t)mode * DD * DD;

    __shared__ __align__(16) float xs[32][DD];   // 24 KB
    const int row0 = blockIdx.x * 32;
    const int t = threadIdx.x;
    {
        const float4* src = (const float4*)(X + (size_t)row0 * DD);
        float4* dst = (float4*)&xs[0][0];
        for (int i = t; i < 32 * DD / 4; i += 384) dst[i] = src[i];
    }
    __syncthreads();

    const int jt = (t % 48) * 4;
    const int rowg = t / 48;           // 0..7, rows rowg*4 .. rowg*4+3

    float acc[4][4];
#pragma unroll
    for (int r = 0; r < 4; ++r)
#pragma unroll
        for (int j = 0; j < 4; ++j) acc[r][j] = 0.f;

#pragma unroll 2
    for (int k4 = 0; k4 < DD / 4; ++k4) {
        float4 w0 = *(const float4*)&WT[(size_t)(k4 * 4 + 0) * DD + jt];
        float4 w1 = *(const float4*)&WT[(size_t)(k4 * 4 + 1) * DD + jt];
        float4 w2 = *(const float4*)&WT[(size_t)(k4 * 4 + 2) * DD + jt];
        float4 w3 = *(const float4*)&WT[(size_t)(k4 * 4 + 3) * DD + jt];
#pragma unroll
        for (int r = 0; r < 4; ++r) {
            float4 xv = *(const float4*)&xs[rowg * 4 + r][k4 * 4];
            acc[r][0] = fmaf(xv.x, w0.x, acc[r][0]); acc[r][1] = fmaf(xv.x, w0.y, acc[r][1]);
            acc[r][2] = fmaf(xv.x, w0.z, acc[r][2]); acc[r][3] = fmaf(xv.x, w0.w, acc[r][3]);
            acc[r][0] = fmaf(xv.y, w1.x, acc[r][0]); acc[r][1] = fmaf(xv.y, w1.y, acc[r][1]);
            acc[r][2] = fmaf(xv.y, w1.z, acc[r][2]); acc[r][3] = fmaf(xv.y, w1.w, acc[r][3]);
            acc[r][0] = fmaf(xv.z, w2.x, acc[r][0]); acc[r][1] = fmaf(xv.z, w2.y, acc[r][1]);
            acc[r][2] = fmaf(xv.z, w2.z, acc[r][2]); acc[r][3] = fmaf(xv.z, w2.w, acc[r][3]);
            acc[r][0] = fmaf(xv.w, w3.x, acc[r][0]); acc[r][1] = fmaf(xv.w, w3.y, acc[r][1]);
            acc[r][2] = fmaf(xv.w, w3.z, acc[r][2]); acc[r][3] = fmaf(xv.w, w3.w, acc[r][3]);
        }
    }

    if (mode < 2) {
        ushort* __restrict__ out = (mode == 0) ? qpad : kpad;
        const int hd = jt / 48, f = jt % 48;
#pragma unroll
        for (int r = 0; r < 4; ++r) {
            ushort4 o;
            o.x = f2bf(acc[r][0]); o.y = f2bf(acc[r][1]);
            o.z = f2bf(acc[r][2]); o.w = f2bf(acc[r][3]);
            *(ushort4*)&out[((size_t)(row0 + rowg * 4 + r) * HH + hd) * 64 + f] = o;
        }
        const int4 z = make_int4(0, 0, 0, 0);
        for (int i = t; i < 256; i += 384) {
            const int row = i >> 3, hh = (i >> 1) & 3, half = i & 1;
            *(int4*)&out[((size_t)(row0 + row) * HH + hh) * 64 + 48 + half * 8] = z;
        }
    } else {
        const int b = row0 >> 11, s0 = row0 & (SS - 1);
#pragma unroll
        for (int j = 0; j < 4; ++j) {
            const int col = jt + j, hd = col / 48, f = col % 48;
#pragma unroll
            for (int p = 0; p < 2; ++p) {
                unsigned pk = (unsigned)f2bf(acc[2 * p][j]) |
                              ((unsigned)f2bf(acc[2 * p + 1][j]) << 16);
                *(unsigned*)&vT[(((size_t)b * HH + hd) * 48 + f) * SS +
                                s0 + rowg * 4 + 2 * p] = pk;
            }
        }
    }
}

// ---------------------------------------------------------------------------
// Output projection via WoT (fp32). 384 thr, 16 rows/block, grid 512.
// Thread: cols jt..jt+3, rows rowg*2..rowg*2+1.
// ---------------------------------------------------------------------------
__global__ __launch_bounds__(384) void o_proj_kernel(
    const float* __restrict__ X, const float* __restrict__ WT,
    float* __restrict__ Y)
{
    __shared__ __align__(16) float xs[16][DD];
    const int row0 = blockIdx.x * 16;
    const int t = threadIdx.x;
    {
        const float4* src = (const float4*)(X + (size_t)row0 * DD);
        float4* dst = (float4*)&xs[0][0];
        for (int i = t; i < 16 * DD / 4; i += 384) dst[i] = src[i];
    }
    __syncthreads();

    const int jt = (t % 48) * 4;
    const int rowg = t / 48;

    float acc[2][4];
#pragma unroll
    for (int r = 0; r < 2; ++r)
#pragma unroll
        for (int j = 0; j < 4; ++j) acc[r][j] = 0.f;

#pragma unroll 2
    for (int k4 = 0; k4 < DD / 4; ++k4) {
        float4 w0 = *(const float4*)&WT[(size_t)(k4 * 4 + 0) * DD + jt];
        float4 w1 = *(const float4*)&WT[(size_t)(k4 * 4 + 1) * DD + jt];
        float4 w2 = *(const float4*)&WT[(size_t)(k4 * 4 + 2) * DD + jt];
        float4 w3 = *(const float4*)&WT[(size_t)(k4 * 4 + 3) * DD + jt];
#pragma unroll
        for (int r = 0; r < 2; ++r) {
            float4 xv = *(const float4*)&xs[rowg * 2 + r][k4 * 4];
            acc[r][0] = fmaf(xv.x, w0.x, acc[r][0]); acc[r][1] = fmaf(xv.x, w0.y, acc[r][1]);
            acc[r][2] = fmaf(xv.x, w0.z, acc[r][2]); acc[r][3] = fmaf(xv.x, w0.w, acc[r][3]);
            acc[r][0] = fmaf(xv.y, w1.x, acc[r][0]); acc[r][1] = fmaf(xv.y, w1.y, acc[r][1]);
            acc[r][2] = fmaf(xv.y, w1.z, acc[r][2]); acc[r][3] = fmaf(xv.y, w1.w, acc[r][3]);
            acc[r][0] = fmaf(xv.z, w2.x, acc[r][0]); acc[r][1] = fmaf(xv.z, w2.y, acc[r][1]);
            acc[r][2] = fmaf(xv.z, w2.z, acc[r][2]); acc[r][3] = fmaf(xv.z, w2.w, acc[r][3]);
            acc[r][0] = fmaf(xv.w, w3.x, acc[r][0]); acc[r][1] = fmaf(xv.w, w3.y, acc[r][1]);
            acc[r][2] = fmaf(xv.w, w3.z, acc[r][2]); acc[r][3] = fmaf(xv.w, w3.w, acc[r][3]);
        }
    }

#pragma unroll
    for (int r = 0; r < 2; ++r)
        *(float4*)&Y[(size_t)(row0 + rowg * 2 + r) * DD + jt] =
            make_float4(acc[r][0], acc[r][1], acc[r][2], acc[r][3]);
}

// ---------------------------------------------------------------------------
// MFMA attention, barrier-free K-loops.
// Block = (b, 16-row q-tile), 8 waves; wave w owns contiguous keys
// [w*256, w*256+256) and ALL 4 heads.  Mask/bias loaded as per-lane scalars
// directly in MFMA D-layout; out1 head-sum in registers; w -> LDS only for
// the PV A-operand transpose (wave-private, fence not barrier).
// Max-free softmax (logits bounded ~45): pass1 accumulates l only.
// PV uses 16x16x32 over 32-key strip pairs; partial PV merged across waves
// at the end via LDS.
// ---------------------------------------------------------------------------
__device__ inline f32x4 qk2(const ushort* kp, const short8 qa0, const short8 qa1) {
    short8 k0 = *(const short8*)kp;
    short8 k1 = *(const short8*)(kp + 32);
    f32x4 d = {0.f, 0.f, 0.f, 0.f};
    d = __builtin_amdgcn_mfma_f32_16x16x32_bf16(qa0, k0, d, 0, 0, 0);
    d = __builtin_amdgcn_mfma_f32_16x16x32_bf16(qa1, k1, d, 0, 0, 0);
    return d;
}

__global__ __launch_bounds__(512, 4) void attn_kernel(
    const ushort* __restrict__ qpad, const ushort* __restrict__ kpad,
    const ushort* __restrict__ vT, const int* __restrict__ mask,
    const float* __restrict__ bias,
    float* __restrict__ out1, float* __restrict__ oattn)
{
    __shared__ __align__(16) ushort w_s[8][HH][16][40];  // 40960 B (stride 80B)
    __shared__ float red_s[8][HH][16];                   // 2048 B
    __shared__ float linv_s[HH][16];                     // 256 B

    const int b  = blockIdx.x >> 7;
    const int q0 = (blockIdx.x & 127) * QT;
    const int t = threadIdx.x;
    const int w = t >> 6, lane = t & 63;
    const int n16 = lane & 15, quad = lane >> 4;
    const int kb0 = w * 256;

    // Q fragments, all 4 heads (A-operand: m=n16, k=quad*8+j [+32])
    short8 qa[HH][2];
    {
        const ushort* qb =
            qpad + ((size_t)(b * SS + q0 + n16) * HH) * 64 + quad * 8;
#pragma unroll
        for (int h = 0; h < HH; ++h) {
            qa[h][0] = *(const short8*)(qb + h * 64);
            qa[h][1] = *(const short8*)(qb + h * 64 + 32);
        }
    }

    const ushort* kptr =
        kpad + ((size_t)(b * SS + kb0 + n16) * HH) * 64 + quad * 8;
    const int* mq = mask + (size_t)(b * SS + q0 + quad * 4) * SS + kb0 + n16;
    const float* bq = bias + (size_t)(q0 + quad * 4) * SS + kb0 + n16;

    // ---------------- PASS 1: denominators (no LDS, no barriers) -----------
    float l_[HH][4];
#pragma unroll
    for (int h = 0; h < HH; ++h)
#pragma unroll
        for (int r = 0; r < 4; ++r) l_[h][r] = 0.f;

#pragma unroll 2
    for (int st = 0; st < 16; ++st) {
        const int o = st * 16;
        int mzr[4];
        float bvr[HH][4];
#pragma unroll
        for (int r = 0; r < 4; ++r) mzr[r] = mq[(size_t)r * SS + o];
#pragma unroll
        for (int h = 0; h < HH; ++h)
#pragma unroll
            for (int r = 0; r < 4; ++r)
                bvr[h][r] = bq[(size_t)h * SS * SS + (size_t)r * SS + o];
#pragma unroll
        for (int h = 0; h < HH; ++h) {
            f32x4 d = qk2(kptr + (size_t)o * (HH * 64) + h * 64, qa[h][0], qa[h][1]);
#pragma unroll
            for (int r = 0; r < 4; ++r) {
                const float lg = mzr[r] ? d[r] + bvr[h][r] : NEG_BIG;
                l_[h][r] += __expf(lg);
            }
        }
    }

    // reduce l over the 16 key-lanes, then across waves
#pragma unroll
    for (int h = 0; h < HH; ++h)
#pragma unroll
        for (int r = 0; r < 4; ++r) {
            float ll = l_[h][r];
            ll += __shfl_xor(ll, 1); ll += __shfl_xor(ll, 2);
            ll += __shfl_xor(ll, 4); ll += __shfl_xor(ll, 8);
            l_[h][r] = ll;
        }
    if (n16 == 0) {
#pragma unroll
        for (int h = 0; h < HH; ++h)
#pragma unroll
            for (int r = 0; r < 4; ++r)
                red_s[w][h][quad * 4 + r] = l_[h][r];
    }
    __syncthreads();
    if (t < 64) {
        const int h = t >> 4, row = t & 15;
        float s = 0.f;
#pragma unroll
        for (int wv = 0; wv < 8; ++wv) s += red_s[wv][h][row];
        linv_s[h][row] = 1.0f / s;
    }
    __syncthreads();
    float linv[HH][4];
#pragma unroll
    for (int h = 0; h < HH; ++h)
#pragma unroll
        for (int r = 0; r < 4; ++r) linv[h][r] = linv_s[h][quad * 4 + r];

    // ---------------- PASS 2: weights + mean + PV (barrier-free) ----------
    f32x4 pv[HH][3];
#pragma unroll
    for (int h = 0; h < HH; ++h)
#pragma unroll
        for (int nb = 0; nb < 3; ++nb) pv[h][nb] = (f32x4){0.f, 0.f, 0.f, 0.f};

    float* o1p = out1 + (size_t)(b * SS + q0 + quad * 4) * SS + kb0 + n16;

    for (int pr = 0; pr < 8; ++pr) {
#pragma unroll
        for (int half = 0; half < 2; ++half) {
            const int st = pr * 2 + half, o = st * 16;
            int mzr[4];
            float bvr[HH][4];
#pragma unroll
            for (int r = 0; r < 4; ++r) mzr[r] = mq[(size_t)r * SS + o];
#pragma unroll
            for (int h = 0; h < HH; ++h)
#pragma unroll
                for (int r = 0; r < 4; ++r)
                    bvr[h][r] = bq[(size_t)h * SS * SS + (size_t)r * SS + o];

            float wsum[4] = {0.f, 0.f, 0.f, 0.f};
#pragma unroll
            for (int h = 0; h < HH; ++h) {
                f32x4 d = qk2(kptr + (size_t)o * (HH * 64) + h * 64,
                              qa[h][0], qa[h][1]);
#pragma unroll
                for (int r = 0; r < 4; ++r) {
                    const float lg = mzr[r] ? d[r] + bvr[h][r] : NEG_BIG;
                    const float wv = __expf(lg) * linv[h][r];
                    wsum[r] += wv;
                    w_s[w][h][quad * 4 + r][half * 16 + n16] = f2bf(wv);
                }
            }
#pragma unroll
            for (int r = 0; r < 4; ++r)
                o1p[(size_t)r * SS + o] = wsum[r] * 0.25f;
        }

        wave_lds_fence();   // w_s pair visible to own wave

#pragma unroll
        for (int h = 0; h < HH; ++h) {
            const short8 a = *(const short8*)&w_s[w][h][n16][quad * 8];
            const ushort* vb = vT + ((size_t)(b * HH + h) * 48 + n16) * SS +
                               kb0 + pr * 32 + quad * 8;
#pragma unroll
            for (int nb = 0; nb < 3; ++nb) {
                short8 v = *(const short8*)(vb + (size_t)nb * 16 * SS);
                pv[h][nb] = __builtin_amdgcn_mfma_f32_16x16x32_bf16(
                    a, v, pv[h][nb], 0, 0, 0);
            }
        }
        wave_lds_fence();   // reads done before next pair overwrites
    }

    // ---------------- merge PV partials across waves ----------------------
    float* scr = (float*)&w_s[0][0][0][0];   // [8][16][50] = 25600 B
#pragma unroll 1
    for (int h = 0; h < HH; ++h) {
        __syncthreads();
#pragma unroll
        for (int nb = 0; nb < 3; ++nb)
#pragma unroll
            for (int r = 0; r < 4; ++r)
                scr[((size_t)w * 16 + quad * 4 + r) * 50 + nb * 16 + n16] =
                    pv[h][nb][r];
        __syncthreads();
        for (int i = t; i < 768; i += 512) {
            const int row = i / 48, f = i % 48;
            float s = 0.f;
#pragma unroll
            for (int wv = 0; wv < 8; ++wv) s += scr[((size_t)wv * 16 + row) * 50 + f];
            oattn[(size_t)(b * SS + q0 + row) * DD + h * 48 + f] = s;
        }
    }
}

// ---------------------------------------------------------------------------
extern "C" void kernel_launch(void* const* d_in, const int* in_sizes, int n_in,
                              void* d_out, int out_size, void* d_ws, size_t ws_size,
                              hipStream_t stream)
{
    const float* query = (const float*)d_in[0];
    const float* key   = (const float*)d_in[1];
    const float* value = (const float*)d_in[2];
    const int*   amask = (const int*)d_in[3];
    const float* bias  = (const float*)d_in[4];
    const float* Wq    = (const float*)d_in[5];
    const float* Wk    = (const float*)d_in[6];
    const float* Wv    = (const float*)d_in[7];
    const float* Wo    = (const float*)d_in[8];

    const size_t n_rows = (size_t)BB * SS;
    float* out0 = (float*)d_out;
    float* out1 = out0 + n_rows * DD;

    ushort* qpad = (ushort*)d_ws;                        // 4 MB
    ushort* kpad = qpad + n_rows * HH * 64;              // 4 MB
    ushort* vT   = kpad + n_rows * HH * 64;              // 3 MB
    float*  oattn = (float*)(vT + (size_t)BB * HH * 48 * SS);   // 6.3 MB
    float*  WTall = oattn + n_rows * DD;                 // 0.59 MB

    wt_kernel<<<dim3(6, 6, 4), 256, 0, stream>>>(Wq, Wk, Wv, Wo, WTall);

    qkv_proj_kernel<<<dim3(n_rows / 32, 3), 384, 0, stream>>>(
        query, key, value, WTall, qpad, kpad, vT);

    attn_kernel<<<dim3(BB * SS / QT), 512, 0, stream>>>(
        qpad, kpad, vT, amask, bias, out1, oattn);

    o_proj_kernel<<<dim3(n_rows / 16), 384, 0, stream>>>(
        oattn, WTall + 3 * DD * DD, out0);
}

// Round 5
// 551.068 us; speedup vs baseline: 1.1046x; 1.1046x over previous
//
#include <hip/hip_runtime.h>

#define BB 4
#define SS 2048
#define HH 4
#define DD 192
#define QT 16
#define NEG_BIG (-1e9f)

typedef __attribute__((ext_vector_type(8))) short short8;
typedef __attribute__((ext_vector_type(4))) float f32x4;

__device__ inline ushort f2bf(float x) {
    union { float f; unsigned u; } v; v.f = x;
    unsigned r = (v.u + 0x7FFFu + ((v.u >> 16) & 1u)) >> 16;
    return (ushort)r;
}
// wave-local LDS fence: drain DS queue + compiler barrier (no block barrier)
__device__ inline void wave_lds_fence() {
    __builtin_amdgcn_wave_barrier();
    __builtin_amdgcn_s_waitcnt(0xC07F);   // vmcnt(63) expcnt(7) lgkmcnt(0)
    __builtin_amdgcn_wave_barrier();
}

// ---------------------------------------------------------------------------
// Transpose the four weight matrices: WT[c][j] = W[j][c].  grid (6,6,4).
// ---------------------------------------------------------------------------
__global__ __launch_bounds__(256) void wt_kernel(
    const float* __restrict__ Wq, const float* __restrict__ Wk,
    const float* __restrict__ Wv, const float* __restrict__ Wo,
    float* __restrict__ WTall)
{
    __shared__ float tile[32][33];
    const float* W = (blockIdx.z == 0) ? Wq : (blockIdx.z == 1) ? Wk
                   : (blockIdx.z == 2) ? Wv : Wo;
    float* WT = WTall + (size_t)blockIdx.z * DD * DD;
    const int c0 = blockIdx.x * 32, j0 = blockIdx.y * 32;
    const int tx = threadIdx.x & 31, ty = threadIdx.x >> 5;
#pragma unroll
    for (int k = 0; k < 4; ++k)
        tile[ty + 8 * k][tx] = W[(size_t)(j0 + ty + 8 * k) * DD + c0 + tx];
    __syncthreads();
#pragma unroll
    for (int k = 0; k < 4; ++k)
        WT[(size_t)(c0 + ty + 8 * k) * DD + j0 + tx] = tile[tx][ty + 8 * k];
}

// ---------------------------------------------------------------------------
// Fused QKV projection via WT. 384 thr (6 waves), 16 rows/block, grid(512,3).
// Thread: cols jt..jt+3, rows rowg*2..rowg*2+1 (2-row groups; xs stride 196
// gives group bank-offsets {0,8,16,24,...} -> only 2-way LDS aliasing).
//   mode 0/1 (q/k): (b,h,s,64) bf16, feature 48..63 zero-padded
//   mode 2   (v)  : (b,h,48,s) bf16 (key-contiguous per feature)
// ---------------------------------------------------------------------------
__global__ __launch_bounds__(384) void qkv_proj_kernel(
    const float* __restrict__ Xq, const float* __restrict__ Xk,
    const float* __restrict__ Xv, const float* __restrict__ WTall,
    ushort* __restrict__ qpad, ushort* __restrict__ kpad,
    ushort* __restrict__ vT)
{
    const int mode = blockIdx.y;
    const float* __restrict__ X = (mode == 0) ? Xq : (mode == 1) ? Xk : Xv;
    const float* __restrict__ WT = WTall + (size_t)mode * DD * DD;

    __shared__ __align__(16) float xs[QT][196];   // 12.25 KB, stride 196
    const int row0 = blockIdx.x * QT;
    const int t = threadIdx.x;
    for (int i = t; i < QT * 48; i += 384) {
        const int row = i / 48, c4 = i % 48;
        *(float4*)&xs[row][c4 * 4] =
            *(const float4*)&X[(size_t)(row0 + row) * DD + c4 * 4];
    }
    __syncthreads();

    const int jt = (t % 48) * 4;
    const int rowg = t / 48;           // 0..7, rows rowg*2, rowg*2+1

    float acc[2][4];
#pragma unroll
    for (int r = 0; r < 2; ++r)
#pragma unroll
        for (int j = 0; j < 4; ++j) acc[r][j] = 0.f;

#pragma unroll 2
    for (int k4 = 0; k4 < DD / 4; ++k4) {
        float4 w0 = *(const float4*)&WT[(size_t)(k4 * 4 + 0) * DD + jt];
        float4 w1 = *(const float4*)&WT[(size_t)(k4 * 4 + 1) * DD + jt];
        float4 w2 = *(const float4*)&WT[(size_t)(k4 * 4 + 2) * DD + jt];
        float4 w3 = *(const float4*)&WT[(size_t)(k4 * 4 + 3) * DD + jt];
#pragma unroll
        for (int r = 0; r < 2; ++r) {
            float4 xv = *(const float4*)&xs[rowg * 2 + r][k4 * 4];
            acc[r][0] = fmaf(xv.x, w0.x, acc[r][0]); acc[r][1] = fmaf(xv.x, w0.y, acc[r][1]);
            acc[r][2] = fmaf(xv.x, w0.z, acc[r][2]); acc[r][3] = fmaf(xv.x, w0.w, acc[r][3]);
            acc[r][0] = fmaf(xv.y, w1.x, acc[r][0]); acc[r][1] = fmaf(xv.y, w1.y, acc[r][1]);
            acc[r][2] = fmaf(xv.y, w1.z, acc[r][2]); acc[r][3] = fmaf(xv.y, w1.w, acc[r][3]);
            acc[r][0] = fmaf(xv.z, w2.x, acc[r][0]); acc[r][1] = fmaf(xv.z, w2.y, acc[r][1]);
            acc[r][2] = fmaf(xv.z, w2.z, acc[r][2]); acc[r][3] = fmaf(xv.z, w2.w, acc[r][3]);
            acc[r][0] = fmaf(xv.w, w3.x, acc[r][0]); acc[r][1] = fmaf(xv.w, w3.y, acc[r][1]);
            acc[r][2] = fmaf(xv.w, w3.z, acc[r][2]); acc[r][3] = fmaf(xv.w, w3.w, acc[r][3]);
        }
    }

    const int b = row0 >> 11, s0 = row0 & (SS - 1);
    if (mode < 2) {
        ushort* __restrict__ out = (mode == 0) ? qpad : kpad;
        const int hd = jt / 48, f = jt % 48;
#pragma unroll
        for (int r = 0; r < 2; ++r) {
            ushort4 o;
            o.x = f2bf(acc[r][0]); o.y = f2bf(acc[r][1]);
            o.z = f2bf(acc[r][2]); o.w = f2bf(acc[r][3]);
            *(ushort4*)&out[((size_t)(b * HH + hd) * SS + s0 + rowg * 2 + r) * 64 + f] = o;
        }
        // zero pad f=48..63 for all 16 rows x 4 heads (ws re-poisoned each launch)
        const int4 z = make_int4(0, 0, 0, 0);
        for (int i = t; i < 128; i += 384) {
            const int row = i >> 3, hh = (i >> 1) & 3, half = i & 1;
            *(int4*)&out[((size_t)(b * HH + hh) * SS + s0 + row) * 64 + 48 + half * 8] = z;
        }
    } else {
#pragma unroll
        for (int j = 0; j < 4; ++j) {
            const int col = jt + j, hd = col / 48, f = col % 48;
            unsigned pk = (unsigned)f2bf(acc[0][j]) |
                          ((unsigned)f2bf(acc[1][j]) << 16);
            *(unsigned*)&vT[(((size_t)b * HH + hd) * 48 + f) * SS + s0 + rowg * 2] = pk;
        }
    }
}

// ---------------------------------------------------------------------------
// MFMA attention + fused O-projection.
// Block = (b, 16-row q-tile), 8 waves; wave w owns keys [w*256, w*256+256),
// all 4 heads.  QK computed as S^T = K·Q^T (A=K, B=Q), so the D-fragment on
// lane (n16,quad) holds S[q0+n16][key = quad*4+r] — 4 CONSECUTIVE keys of one
// q-row.  Mask (int4), bias (float4) and out1 (float4) are therefore fully
// coalesced per-lane vector ops in-register.  PV: the same layout IS the
// 16x16x32 A-operand layout per 16-key strip up to quad-granularity; a
// wave-private 8B LDS write + fence assembles 32-key A fragments.
// Max-free softmax (|logit| <~ 45 << 88): pass1 accumulates l only.
// Epilogue: merge PV partials across waves into a 16x192 LDS tile, then
// compute out0 = tile @ Wo^T right here (no o_proj kernel).
// ---------------------------------------------------------------------------
__global__ __launch_bounds__(512, 4) void attn_kernel(
    const ushort* __restrict__ qpad, const ushort* __restrict__ kpad,
    const ushort* __restrict__ vT, const int* __restrict__ mask,
    const float* __restrict__ bias, const float* __restrict__ WoT,
    float* __restrict__ out0, float* __restrict__ out1)
{
    __shared__ __align__(16) ushort w_lds[8][HH][QT][36];  // 36864 B
    __shared__ __align__(16) float otile[QT][196];         // 12544 B
    __shared__ float red_s[8][HH][QT];                     // 2048 B
    __shared__ float linv_s[HH][QT];                       // 256 B

    const int b  = blockIdx.x >> 7;
    const int q0 = (blockIdx.x & 127) * QT;
    const int t = threadIdx.x;
    const int w = t >> 6, lane = t & 63;
    const int n16 = lane & 15, quad = lane >> 4;
    const int kb0 = w * 256;

    // Q fragments (B-operand: n=n16=qrow, k=quad*8+j feats), all 4 heads
    short8 qa[HH][2];
#pragma unroll
    for (int h = 0; h < HH; ++h) {
        const ushort* qb =
            qpad + ((size_t)(b * HH + h) * SS + q0 + n16) * 64 + quad * 8;
        qa[h][0] = *(const short8*)(qb);
        qa[h][1] = *(const short8*)(qb + 32);
    }
    // K base (A-operand: m=n16=key-in-16, k=quad*8+j feats)
    const ushort* kb_[HH];
#pragma unroll
    for (int h = 0; h < HH; ++h)
        kb_[h] = kpad + ((size_t)(b * HH + h) * SS + kb0 + n16) * 64 + quad * 8;

    const int* mp = mask + ((size_t)(b * SS + q0 + n16)) * SS + kb0 + quad * 4;
    const float* bp = bias + ((size_t)(q0 + n16)) * SS + kb0 + quad * 4;

    // ---------------- PASS 1: denominators (no LDS, no barriers) -----------
    float l_[HH] = {0.f, 0.f, 0.f, 0.f};
#pragma unroll 4
    for (int tile = 0; tile < 16; ++tile) {
        const int4 mz = *(const int4*)(mp + tile * 16);
#pragma unroll
        for (int h = 0; h < HH; ++h) {
            const float4 bv = *(const float4*)(bp + (size_t)h * SS * SS + tile * 16);
            const ushort* kp = kb_[h] + (size_t)tile * 16 * 64;
            short8 k0 = *(const short8*)(kp);
            short8 k1 = *(const short8*)(kp + 32);
            f32x4 d = {0.f, 0.f, 0.f, 0.f};
            d = __builtin_amdgcn_mfma_f32_16x16x32_bf16(k0, qa[h][0], d, 0, 0, 0);
            d = __builtin_amdgcn_mfma_f32_16x16x32_bf16(k1, qa[h][1], d, 0, 0, 0);
            l_[h] += __expf(mz.x ? d[0] + bv.x : NEG_BIG) +
                     __expf(mz.y ? d[1] + bv.y : NEG_BIG) +
                     __expf(mz.z ? d[2] + bv.z : NEG_BIG) +
                     __expf(mz.w ? d[3] + bv.w : NEG_BIG);
        }
    }
    // sum over quads (keys) -> per-(wave,row) partial, then across waves
#pragma unroll
    for (int h = 0; h < HH; ++h) {
        float ll = l_[h];
        ll += __shfl_xor(ll, 16);
        ll += __shfl_xor(ll, 32);
        if (quad == 0) red_s[w][h][n16] = ll;
    }
    __syncthreads();
    if (t < 64) {
        const int h = t >> 4, row = t & 15;
        float s = 0.f;
#pragma unroll
        for (int wv = 0; wv < 8; ++wv) s += red_s[wv][h][row];
        linv_s[h][row] = 1.0f / s;
    }
    __syncthreads();
    float linv[HH];
#pragma unroll
    for (int h = 0; h < HH; ++h) linv[h] = linv_s[h][n16];

    // ---------------- PASS 2: weights + out1 + PV (barrier-free) ----------
    f32x4 pv[HH][3];
#pragma unroll
    for (int h = 0; h < HH; ++h)
#pragma unroll
        for (int nb = 0; nb < 3; ++nb) pv[h][nb] = (f32x4){0.f, 0.f, 0.f, 0.f};

    float* o1p = out1 + ((size_t)(b * SS + q0 + n16)) * SS + kb0 + quad * 4;

    for (int pr = 0; pr < 8; ++pr) {
#pragma unroll
        for (int tt = 0; tt < 2; ++tt) {
            const int tile = pr * 2 + tt;
            const int4 mz = *(const int4*)(mp + tile * 16);
            float ws0 = 0.f, ws1 = 0.f, ws2 = 0.f, ws3 = 0.f;
#pragma unroll
            for (int h = 0; h < HH; ++h) {
                const float4 bv = *(const float4*)(bp + (size_t)h * SS * SS + tile * 16);
                const ushort* kp = kb_[h] + (size_t)tile * 16 * 64;
                short8 k0 = *(const short8*)(kp);
                short8 k1 = *(const short8*)(kp + 32);
                f32x4 d = {0.f, 0.f, 0.f, 0.f};
                d = __builtin_amdgcn_mfma_f32_16x16x32_bf16(k0, qa[h][0], d, 0, 0, 0);
                d = __builtin_amdgcn_mfma_f32_16x16x32_bf16(k1, qa[h][1], d, 0, 0, 0);
                float w0 = __expf(mz.x ? d[0] + bv.x : NEG_BIG) * linv[h];
                float w1 = __expf(mz.y ? d[1] + bv.y : NEG_BIG) * linv[h];
                float w2 = __expf(mz.z ? d[2] + bv.z : NEG_BIG) * linv[h];
                float w3 = __expf(mz.w ? d[3] + bv.w : NEG_BIG) * linv[h];
                ws0 += w0; ws1 += w1; ws2 += w2; ws3 += w3;
                ushort4 wp;
                wp.x = f2bf(w0); wp.y = f2bf(w1); wp.z = f2bf(w2); wp.w = f2bf(w3);
                *(ushort4*)&w_lds[w][h][n16][tt * 16 + quad * 4] = wp;
            }
            *(float4*)(o1p + tile * 16) =
                make_float4(ws0 * 0.25f, ws1 * 0.25f, ws2 * 0.25f, ws3 * 0.25f);
        }
        wave_lds_fence();   // own wave's 32-key w strip visible

#pragma unroll
        for (int h = 0; h < HH; ++h) {
            const short8 a = *(const short8*)&w_lds[w][h][n16][quad * 8];
            const ushort* vb = vT + (((size_t)b * HH + h) * 48 + n16) * SS +
                               kb0 + pr * 32 + quad * 8;
#pragma unroll
            for (int nb = 0; nb < 3; ++nb) {
                short8 v = *(const short8*)(vb + (size_t)nb * 16 * SS);
                pv[h][nb] = __builtin_amdgcn_mfma_f32_16x16x32_bf16(
                    a, v, pv[h][nb], 0, 0, 0);
            }
        }
        wave_lds_fence();   // reads done before next strip overwrites
    }

    // ---------------- merge PV across waves into otile --------------------
    __syncthreads();   // all waves done with w_lds before aliasing as scr
    float* scr = (float*)&w_lds[0][0][0][0];   // [8][16][52] floats = 26624 B
#pragma unroll 1
    for (int h = 0; h < HH; ++h) {
#pragma unroll
        for (int nb = 0; nb < 3; ++nb)
#pragma unroll
            for (int r = 0; r < 4; ++r)
                scr[((size_t)w * QT + quad * 4 + r) * 52 + nb * 16 + n16] =
                    pv[h][nb][r];
        __syncthreads();
        for (int i = t; i < QT * 48; i += 512) {
            const int row = i / 48, f = i % 48;
            float s = 0.f;
#pragma unroll
            for (int wv = 0; wv < 8; ++wv)
                s += scr[((size_t)wv * QT + row) * 52 + f];
            otile[row][h * 48 + f] = s;
        }
        __syncthreads();
    }

    // ---------------- fused O-projection: out0 = otile @ Wo^T -------------
    for (int i = t; i < QT * 48; i += 512) {
        const int row = i / 48, c4 = i % 48;
        float a0 = 0.f, a1 = 0.f, a2 = 0.f, a3 = 0.f;
#pragma unroll 4
        for (int k = 0; k < DD; ++k) {
            const float x = otile[row][k];
            const float4 wv = *(const float4*)&WoT[(size_t)k * DD + c4 * 4];
            a0 = fmaf(x, wv.x, a0); a1 = fmaf(x, wv.y, a1);
            a2 = fmaf(x, wv.z, a2); a3 = fmaf(x, wv.w, a3);
        }
        *(float4*)&out0[(size_t)(b * SS + q0 + row) * DD + c4 * 4] =
            make_float4(a0, a1, a2, a3);
    }
}

// ---------------------------------------------------------------------------
extern "C" void kernel_launch(void* const* d_in, const int* in_sizes, int n_in,
                              void* d_out, int out_size, void* d_ws, size_t ws_size,
                              hipStream_t stream)
{
    const float* query = (const float*)d_in[0];
    const float* key   = (const float*)d_in[1];
    const float* value = (const float*)d_in[2];
    const int*   amask = (const int*)d_in[3];
    const float* bias  = (const float*)d_in[4];
    const float* Wq    = (const float*)d_in[5];
    const float* Wk    = (const float*)d_in[6];
    const float* Wv    = (const float*)d_in[7];
    const float* Wo    = (const float*)d_in[8];

    const size_t n_rows = (size_t)BB * SS;
    float* out0 = (float*)d_out;
    float* out1 = out0 + n_rows * DD;

    ushort* qpad = (ushort*)d_ws;                        // 4.2 MB
    ushort* kpad = qpad + (size_t)BB * HH * SS * 64;     // 4.2 MB
    ushort* vT   = kpad + (size_t)BB * HH * SS * 64;     // 3.1 MB
    float*  WTall = (float*)(vT + (size_t)BB * HH * 48 * SS);  // 0.59 MB

    wt_kernel<<<dim3(6, 6, 4), 256, 0, stream>>>(Wq, Wk, Wv, Wo, WTall);

    qkv_proj_kernel<<<dim3(n_rows / QT, 3), 384, 0, stream>>>(
        query, key, value, WTall, qpad, kpad, vT);

    attn_kernel<<<dim3(BB * SS / QT), 512, 0, stream>>>(
        qpad, kpad, vT, amask, bias, WTall + 3 * DD * DD, out0, out1);
}